// Round 7
// baseline (58.581 us; speedup 1.0000x reference)
//
#include <hip/hip_runtime.h>
#include <math.h>

// Problem constants
#define BB 512
#define VV 2
#define MM 1024
#define DD 128
#define KMAX 50
#define TOPK 15
#define INV_T (1.0f/0.07f)

// ---------------- Workspace layout (byte offsets) ----------------
#define OFF_ANCH   0                     // bf16 [MM][DD]   256 KB
#define OFF_A2     262144                // f32  [MM]         4 KB
#define OFF_ACCT   266240                // f32  [BB][MM]     2 MB : accT[b][i] = acc(i,b)
#define OFF_ROWSUM 2363392               // f32  [MM]         4 KB : exp-sum per row (atomic)
#define OFF_POSSUM 2367488               // f32  [64]        256 B : sum of positive logits (atomic)
#define OFF_CNT    2367744               // u32  [1]               : finished-block counter

typedef __attribute__((ext_vector_type(8))) short bf16x8;
typedef __attribute__((ext_vector_type(4))) float f32x4;

// f32 -> bf16 (RNE)
__device__ __forceinline__ short f2bf(float x)
{
    union { float f; unsigned u; } a; a.f = x;
    return (short)((a.u + 0x7FFFu + ((a.u >> 16) & 1u)) >> 16);
}

// convert 8 f32 (two float4) to bf16x8, accumulating sum of squares
__device__ __forceinline__ bf16x8 cvt8(float4 p0, float4 p1, float& nacc)
{
    float v[8] = {p0.x, p0.y, p0.z, p0.w, p1.x, p1.y, p1.z, p1.w};
    bf16x8 r;
    #pragma unroll
    for (int e = 0; e < 8; ++e) {
        nacc = fmaf(v[e], v[e], nacc);
        r[e] = f2bf(v[e]);
    }
    return r;
}

// ---------------------------------------------------------------------------
// K0: anchor (transposed features) -> bf16 + exact f32 norms.
// Block 0 additionally zeroes the atomic accumulators (ws is poisoned 0xAA).
// 256 blocks x 256 thr; wave per row.
// ---------------------------------------------------------------------------
__global__ __launch_bounds__(256) void k0_anchor(
    const float* __restrict__ feat,
    unsigned* __restrict__ anchor_u,     // bf16 pairs packed as u32
    float* __restrict__ a2,
    float* __restrict__ rowsum, float* __restrict__ possum,
    unsigned* __restrict__ cnt)
{
    const int tid  = threadIdx.x;
    const int row  = blockIdx.x * 4 + (tid >> 6);
    const int lane = tid & 63;
    const int frow = (row & (BB - 1)) * VV + (row >> 9);
    float2 v = *(const float2*)&feat[(size_t)frow * DD + lane * 2];
    unsigned lo = (unsigned)(unsigned short)f2bf(v.x);
    unsigned hi = (unsigned)(unsigned short)f2bf(v.y);
    anchor_u[row * (DD / 2) + lane] = lo | (hi << 16);
    float sq = v.x * v.x + v.y * v.y;
    #pragma unroll
    for (int off = 32; off > 0; off >>= 1) sq += __shfl_xor(sq, off);
    if (lane == 0) a2[row] = sq;

    if (blockIdx.x == 0) {               // zero the atomic accumulators
        #pragma unroll
        for (int q = 0; q < 4; ++q) rowsum[tid + q * 256] = 0.f;
        if (tid < 64) possum[tid] = 0.f;
        if (tid == 0) *cnt = 0u;
    }
}

// ---------------------------------------------------------------------------
// K1: neighbor MFMA GEMM -> accT[b][i].
// Grid (512): one block per b-group. The 16 gathered saved-rows (bf16 frags +
// exact norms) are loaded ONCE and reused across all 1024 anchor columns
// (each of 4 waves owns 256 cols = 4 tiles of 64). Unique gather = 1x.
// C layout (mfma_f32_16x16x32_bf16): col = lane&15, row(k) = (lane>>4)*4 + reg.
// ---------------------------------------------------------------------------
__global__ __launch_bounds__(256) void k1_acc(
    const short* __restrict__ anchor,    // bf16 [MM][DD]
    const float* __restrict__ a2,
    const int* __restrict__ indices,
    const float* __restrict__ saved, const int* __restrict__ rks,
    float* __restrict__ accT)
{
    const int tid = threadIdx.x;
    const int lane = tid & 63;
    const int wid = tid >> 6;
    const int lr = lane & 15;
    const int lg = lane >> 4;
    const int b = blockIdx.x;

    const int aidx = rks[(size_t)indices[b] * KMAX + lr];   // k = lr (15 masked)

    bf16x8 af[4];
    float nnA = 0.f;
    #pragma unroll
    for (int kc = 0; kc < 4; ++kc) {
        const float4* p = (const float4*)&saved[(size_t)aidx * DD + kc * 32 + lg * 8];
        af[kc] = cvt8(p[0], p[1], nnA);
    }
    nnA += __shfl_xor(nnA, 16);
    nnA += __shfl_xor(nnA, 32);          // lane holds full norm of row lr
    float nnAr[4];
    #pragma unroll
    for (int r = 0; r < 4; ++r)
        nnAr[r] = __shfl(nnA, lg * 4 + r);   // norm of C-row (k = lg*4 + r)

    #pragma unroll
    for (int jt = 0; jt < 4; ++jt) {
        const int j0 = wid * 256 + jt * 64;
        f32x4 acc[4];
        #pragma unroll
        for (int t = 0; t < 4; ++t) acc[t] = (f32x4){0.f, 0.f, 0.f, 0.f};
        #pragma unroll
        for (int kc = 0; kc < 4; ++kc) {
            bf16x8 bf[4];
            #pragma unroll
            for (int tn = 0; tn < 4; ++tn)
                bf[tn] = *(const bf16x8*)&anchor[(size_t)(j0 + tn * 16 + lr) * DD + kc * 32 + lg * 8];
            #pragma unroll
            for (int tn = 0; tn < 4; ++tn)
                acc[tn] = __builtin_amdgcn_mfma_f32_16x16x32_bf16(
                    af[kc], bf[tn], acc[tn], 0, 0, 0);
        }
        #pragma unroll
        for (int tn = 0; tn < 4; ++tn) {
            const float a2j = a2[j0 + tn * 16 + lr];
            float s = 0.f;
            #pragma unroll
            for (int r = 0; r < 4; ++r) {
                float g = acc[tn][r];
                float sq = fmaxf(fmaf(-2.f, g, a2j + nnAr[r]), 0.f);
                float d = __builtin_amdgcn_sqrtf(sq);
                float f = fmaf(__builtin_amdgcn_rcpf(1.f + d), INV_T, INV_T);
                if (lg == 3 && r == 3) f = 0.f;          // k == 15 pad row
                s += f;
            }
            s += __shfl_xor(s, 16);
            s += __shfl_xor(s, 32);                      // sum the 16 k-rows
            if (lane < 16)
                accT[(size_t)b * MM + j0 + tn * 16 + lane] = s * (1.0f / TOPK);
        }
    }
}

// ---------------------------------------------------------------------------
// K2: S-tile MFMA + adc + ls + exp, accumulated into rowsum/possum via
// device-scope atomics; the LAST block to finish computes the final loss.
// (No max subtraction: ls in [24.7, 49.5], exp-sum <= 3e24 fits fp32;
//  verified rounds 4-6, absmax 0.)
// Grid (64, 16): 16 i-rows x 64 j-cols per block; wave handles 16 cols.
// ---------------------------------------------------------------------------
__global__ __launch_bounds__(256) void k2_exp(
    const short* __restrict__ anchor, const float* __restrict__ a2,
    const float* __restrict__ accT,
    float* __restrict__ rowsum, float* __restrict__ possum,
    unsigned* __restrict__ cnt, float* __restrict__ out)
{
    __shared__ float pshare[4][16];
    __shared__ float red[4];
    __shared__ int iswin;
    const int tid = threadIdx.x;
    const int lane = tid & 63;
    const int wid = tid >> 6;
    const int lr = lane & 15;
    const int lg = lane >> 4;
    const int i0 = blockIdx.x * 16;
    const int jg = blockIdx.y;
    const int jcol = jg * 64 + wid * 16 + lr;

    f32x4 acc = (f32x4){0.f, 0.f, 0.f, 0.f};
    #pragma unroll
    for (int kc = 0; kc < 4; ++kc) {
        bf16x8 af = *(const bf16x8*)&anchor[(size_t)(i0 + lr) * DD + kc * 32 + lg * 8];
        bf16x8 bf = *(const bf16x8*)&anchor[(size_t)jcol * DD + kc * 32 + lg * 8];
        acc = __builtin_amdgcn_mfma_f32_16x16x32_bf16(af, bf, acc, 0, 0, 0);
    }
    const int ib4 = i0 + lg * 4;
    const float4 a2i4 = *(const float4*)&a2[ib4];
    const float a2iv[4] = {a2i4.x, a2i4.y, a2i4.z, a2i4.w};
    const float a2j = a2[jcol];
    const float4 aij4 = *(const float4*)&accT[(size_t)(jcol & (BB - 1)) * MM + ib4];
    const float aijv[4] = {aij4.x, aij4.y, aij4.z, aij4.w};

    float esum[4];
    #pragma unroll
    for (int r = 0; r < 4; ++r) {
        const int i = ib4 + r;
        float g = acc[r];
        float sq = fmaxf(fmaf(-2.f, g, a2iv[r] + a2j), 0.f);
        float d0 = __builtin_amdgcn_sqrtf(sq);
        float adc = fmaf(__builtin_amdgcn_rcpf(1.f + d0), INV_T, INV_T);
        float aji = accT[(size_t)(i & (BB - 1)) * MM + jcol];
        float ls = __builtin_amdgcn_sqrtf(aijv[r] * aijv[r] + aji * aji + adc * adc);
        esum[r] = (jcol == i) ? 0.f : __expf(ls);
        if (jcol == (i ^ BB)) atomicAdd(&possum[i & 63], ls);  // the positive pair
    }
    #pragma unroll
    for (int r = 0; r < 4; ++r) {
        float e = esum[r];
        e += __shfl_xor(e, 1);
        e += __shfl_xor(e, 2);
        e += __shfl_xor(e, 4);
        e += __shfl_xor(e, 8);                           // sum 16 j's in wave
        if (lr == 0) pshare[wid][lg * 4 + r] = e;
    }
    __syncthreads();                                     // pshare + possum drained
    if (tid < 16)
        atomicAdd(&rowsum[i0 + tid],
                  pshare[0][tid] + pshare[1][tid] + pshare[2][tid] + pshare[3][tid]);
    __syncthreads();                                     // rowsum atomics drained
    if (tid == 0) {
        unsigned old = __hip_atomic_fetch_add(cnt, 1u, __ATOMIC_ACQ_REL,
                                              __HIP_MEMORY_SCOPE_AGENT);
        iswin = (old == 64u * 16u - 1u);
    }
    __syncthreads();
    if (!iswin) return;

    // -------- last block: finish. loss = mean(log(rowsum) - lspos) --------
    float lsum = 0.f;
    #pragma unroll
    for (int q = 0; q < 4; ++q) {
        const int i = tid + q * 256;
        float rs = __hip_atomic_load(&rowsum[i], __ATOMIC_RELAXED,
                                     __HIP_MEMORY_SCOPE_AGENT);
        lsum += __logf(rs);
    }
    if (tid < 64)
        lsum -= __hip_atomic_load(&possum[tid], __ATOMIC_RELAXED,
                                  __HIP_MEMORY_SCOPE_AGENT);
    #pragma unroll
    for (int off = 32; off > 0; off >>= 1) lsum += __shfl_xor(lsum, off);
    if (lane == 0) red[wid] = lsum;
    __syncthreads();
    if (tid == 0)
        out[0] = (red[0] + red[1] + red[2] + red[3]) * (1.0f / MM);
}

// ---------------------------------------------------------------------------
extern "C" void kernel_launch(void* const* d_in, const int* in_sizes, int n_in,
                              void* d_out, int out_size, void* d_ws, size_t ws_size,
                              hipStream_t stream)
{
    const float* feat    = (const float*)d_in[0];  // (512, 2, 128) f32
    const int*   indices = (const int*)  d_in[1];  // (512,) i32
    const float* saved   = (const float*)d_in[2];  // (100000, 128) f32
    const int*   rks     = (const int*)  d_in[3];  // (100000, 50) i32

    char* w = (char*)d_ws;
    short*    anchor = (short*)   (w + OFF_ANCH);
    float*    a2     = (float*)   (w + OFF_A2);
    float*    accT   = (float*)   (w + OFF_ACCT);
    float*    rowsum = (float*)   (w + OFF_ROWSUM);
    float*    possum = (float*)   (w + OFF_POSSUM);
    unsigned* cnt    = (unsigned*)(w + OFF_CNT);

    // K0: anchor -> bf16 + exact norms; zero atomic accumulators
    k0_anchor<<<MM / 4, 256, 0, stream>>>(feat, (unsigned*)anchor, a2,
                                          rowsum, possum, cnt);
    // K1: neighbor GEMM -> accT (each saved row gathered exactly once)
    k1_acc<<<BB, 256, 0, stream>>>(anchor, a2, indices, saved, rks, accT);
    // K2: S-GEMM + adc + exp -> atomic rowsum/possum; last block finishes
    k2_exp<<<dim3(64, 16), 256, 0, stream>>>(anchor, a2, accT,
                                             rowsum, possum, cnt, (float*)d_out);
}